// Round 11
// baseline (161.990 us; speedup 1.0000x reference)
//
#include <hip/hip_runtime.h>

// LaplacianLoss on a fixed 512x512 grid mesh, B=32.
// Lv[b,(i,j)] = v - (1/deg)*sum(nbrs), nbrs = (i,j+-1),(i+-1,j),(i-1,j+1),(i+1,j-1)
// out = mean over (B,V) of |Lv|^2.
//
// R10 lesson: kernel is VALU-bound (~28us VALU vs ~16us HBM; MLP analysis
// shows latency was always hidden). R11: (1) packed fp32 math via
// ext_vector_type(2) -> v_pk_add/fma_f32 halves arithmetic; (2) interior/edge
// template split removes masks/clamps/inv-selects from 14/16 blocks;
// (3) RI=32 -> 512 blocks = exactly 2 blocks/CU, no residency tail.

typedef float f2 __attribute__((ext_vector_type(2)));

#define GH 512
#define GW 512
#define GV (GH * GW)
#define ROWF 1536                // floats per row
#define RQ 384                   // float4s per row = threads per block
#define RI 32                    // center rows per block
#define NITER (RI + 4)           // 36 (multiple of 4 for slot cycling)
#define NCH 16                   // chunks per batch
#define NBLK (32 * NCH)          // 512 blocks

template<bool EDGE>
__device__ __forceinline__ f2 run_chunk(const float* __restrict__ base,
                                        const int i0, const int lane,
                                        const int t, const int dh,
                                        const float mH) {
    // -1/deg per element (mid; top/bottom only for EDGE)
    f2 invMlo, invMhi, invTlo, invThi, invBlo, invBhi;
    {
        float im[4], it[4], ib[4];
        #pragma unroll
        for (int e = 0; e < 4; ++e) {
            const int q = 4 * t + e;
            const float jl = (q >= 3) ? 1.f : 0.f;
            const float jr = (q < ROWF - 3) ? 1.f : 0.f;
            im[e] = -1.f / (2.f + 2.f * jl + 2.f * jr);
            it[e] = -1.f / (1.f + 2.f * jl + jr);
            ib[e] = -1.f / (1.f + jl + 2.f * jr);
        }
        invMlo = (f2){im[0], im[1]}; invMhi = (f2){im[2], im[3]};
        invTlo = (f2){it[0], it[1]}; invThi = (f2){it[2], it[3]};
        invBlo = (f2){ib[0], ib[1]}; invBhi = (f2){ib[2], ib[3]};
    }

    // depth-4 named prefetch slots: rows i0-1 .. i0+2
    float4 Qs0, Qs1, Qs2, Qs3, Hs0, Hs1, Hs2, Hs3;
    {
        const int r0 = EDGE ? max(i0 - 1, 0) : (i0 - 1);
        const float* rp;
        rp = base + (size_t)r0 * ROWF;       Qs0 = *(const float4*)rp; Hs0 = *(const float4*)(rp + dh);
        rp = base + (size_t)(i0 + 0) * ROWF; Qs1 = *(const float4*)rp; Hs1 = *(const float4*)(rp + dh);
        rp = base + (size_t)(i0 + 1) * ROWF; Qs2 = *(const float4*)rp; Hs2 = *(const float4*)(rp + dh);
        rp = base + (size_t)(i0 + 2) * ROWF; Qs3 = *(const float4*)rp; Hs3 = *(const float4*)(rp + dh);
    }

    // carried combos: T2=T(c-1), T1=T(c), M1=M(c), C1=Q(c)
    f2 T2lo = {0.f, 0.f}, T2hi = T2lo, T1lo = T2lo, T1hi = T2lo;
    f2 M1lo = T2lo, M1hi = T2lo, C1lo = T2lo, C1hi = T2lo;
    f2 acc = {0.f, 0.f};

#define ITER(K, QS, HS)                                                      \
    {                                                                        \
        const int k = (K);                                                   \
        const float4 Qf = QS;                                                \
        const float4 Hf = HS;                                                \
        /* refill slot with row i0+3+k (consumed at k+4) */                  \
        {                                                                    \
            int rn = i0 + 3 + k;                                             \
            if (EDGE) rn = min(rn, GH - 1);                                  \
            const float* rp = base + (size_t)rn * ROWF;                      \
            QS = *(const float4*)rp;                                         \
            HS = *(const float4*)(rp + dh);                                  \
        }                                                                    \
        float hm = mH;                                                       \
        f2 Qlo = {Qf.x, Qf.y}, Qhi = {Qf.z, Qf.w};                           \
        if (EDGE) {                                                          \
            const int r = i0 - 1 + k;                                        \
            const float mrow = (r >= 0 && r < GH) ? 1.f : 0.f;               \
            hm = mH * mrow;                                                  \
            Qlo *= mrow; Qhi *= mrow;                                        \
        }                                                                    \
        const f2 Hxy = (f2){Hf.x, Hf.y} * hm;                                \
        const f2 Hzw = (f2){Hf.z, Hf.w} * hm;                                \
        const float py = __shfl_up(Qlo.y, 1, 64);                            \
        const float pz = __shfl_up(Qhi.x, 1, 64);                            \
        const float pw = __shfl_up(Qhi.y, 1, 64);                            \
        const float nx = __shfl_down(Qlo.x, 1, 64);                          \
        const float ny = __shfl_down(Qlo.y, 1, 64);                          \
        const float nz = __shfl_down(Qhi.x, 1, 64);                          \
        const f2 Qm3lo = {(lane == 0) ? Hxy.y : py,                          \
                          (lane == 0) ? Hzw.x : pz};                         \
        const f2 Qm3hi = {(lane == 0) ? Hzw.y : pw, Qlo.x};                  \
        const f2 Qp3lo = {Qhi.y, (lane == 63) ? Hxy.x : nx};                 \
        const f2 Qp3hi = {(lane == 63) ? Hxy.y : ny,                         \
                          (lane == 63) ? Hzw.x : nz};                        \
        const f2 Bnlo = Qlo + Qm3lo, Bnhi = Qhi + Qm3hi;                     \
        const f2 Tnlo = Qlo + Qp3lo, Tnhi = Qhi + Qp3hi;                     \
        const f2 Mnlo = Qm3lo + Qp3lo, Mnhi = Qm3hi + Qp3hi;                 \
        if (k >= 2 && k < RI + 2) {                                          \
            f2 invlo = invMlo, invhi = invMhi;                               \
            if (EDGE) {                                                      \
                const int c = i0 + k - 2;                                    \
                const bool ct = (c == 0), cb = (c == GH - 1);                \
                invlo = ct ? invTlo : (cb ? invBlo : invMlo);                \
                invhi = ct ? invThi : (cb ? invBhi : invMhi);                \
            }                                                                \
            const f2 slo = T2lo + M1lo + Bnlo;                               \
            const f2 shi = T2hi + M1hi + Bnhi;                               \
            const f2 lvlo = invlo * slo + C1lo;                              \
            const f2 lvhi = invhi * shi + C1hi;                              \
            acc += lvlo * lvlo;                                              \
            acc += lvhi * lvhi;                                              \
        }                                                                    \
        T2lo = T1lo; T2hi = T1hi; T1lo = Tnlo; T1hi = Tnhi;                  \
        M1lo = Mnlo; M1hi = Mnhi; C1lo = Qlo; C1hi = Qhi;                    \
    }

    for (int kb = 0; kb < NITER; kb += 4) {
        ITER(kb + 0, Qs0, Hs0);
        ITER(kb + 1, Qs1, Hs1);
        ITER(kb + 2, Qs2, Hs2);
        ITER(kb + 3, Qs3, Hs3);
    }
#undef ITER

    return acc;
}

__global__ __launch_bounds__(RQ, 4) void lap_partial_kernel(
    const float* __restrict__ verts, float* __restrict__ partials) {
    const int bid   = blockIdx.x;
    const int batch = bid >> 4;
    const int chunk = bid & (NCH - 1);
    const int i0    = chunk * RI;
    const int t     = threadIdx.x;       // owns floats [4t, 4t+4) of each row
    const int lane  = t & 63;
    const float* __restrict__ base = verts + (size_t)batch * (GV * 3) + 4 * t;

    // halo: one always-executed float4 per row at per-lane constant offset
    const float mH = ((lane == 0 && t > 0) || (lane == 63 && t < RQ - 1)) ? 1.f : 0.f;
    const int dh = (lane == 0) ? ((t > 0) ? -4 : 0)
                 : ((lane == 63) ? ((t < RQ - 1) ? 4 : 0) : 0);

    f2 acc;
    if (chunk == 0 || chunk == NCH - 1)
        acc = run_chunk<true>(base, i0, lane, t, dh, mH);
    else
        acc = run_chunk<false>(base, i0, lane, t, dh, mH);

    float local = acc.x + acc.y;

    // block reduction: wave shuffle -> LDS -> one store per block
    #pragma unroll
    for (int off = 32; off > 0; off >>= 1)
        local += __shfl_down(local, off, 64);

    __shared__ float wsum[6];
    const int wave = t >> 6;
    if (lane == 0) wsum[wave] = local;
    __syncthreads();
    if (t == 0) {
        float s = wsum[0];
        #pragma unroll
        for (int w = 1; w < 6; ++w) s += wsum[w];
        partials[bid] = s;
    }
}

__global__ __launch_bounds__(256) void lap_final_kernel(
    const float* __restrict__ partials, float* __restrict__ out, int nblk, int B) {
    float local = 0.0f;
    for (int k = threadIdx.x; k < nblk; k += 256)
        local += partials[k];

    #pragma unroll
    for (int off = 32; off > 0; off >>= 1)
        local += __shfl_down(local, off, 64);

    __shared__ float wsum[4];
    const int lane = threadIdx.x & 63;
    const int wid  = threadIdx.x >> 6;
    if (lane == 0) wsum[wid] = local;
    __syncthreads();

    if (threadIdx.x == 0) {
        const float s = wsum[0] + wsum[1] + wsum[2] + wsum[3];
        out[0] = s / ((float)B * (float)GV);
    }
}

extern "C" void kernel_launch(void* const* d_in, const int* in_sizes, int n_in,
                              void* d_out, int out_size, void* d_ws, size_t ws_size,
                              hipStream_t stream) {
    const float* verts = (const float*)d_in[0];
    float* out = (float*)d_out;
    float* partials = (float*)d_ws;            // 512 floats = 2 KB

    const int B = in_sizes[0] / (GV * 3);      // 32

    lap_partial_kernel<<<NBLK, RQ, 0, stream>>>(verts, partials);
    lap_final_kernel<<<1, 256, 0, stream>>>(partials, out, NBLK, B);
}